// Round 8
// baseline (1467.085 us; speedup 1.0000x reference)
//
#include <hip/hip_runtime.h>
#include <hip/hip_bf16.h>

#define NN 100000
#define EE 3200000
#define CC 64
#define NC (NN*CC)
#define ERR_BLOCKS 6250        // NC/4/256
#define NB 391                 // buckets = key>>8, ceil(NN/256)
#define TILE 8192              // edges per binning block
#define NTILE 391              // ceil(EE/TILE)

// ---------------- helpers ----------------
__device__ __forceinline__ float ldf(const void* p, long i, int isbf) {
    if (isbf) {
        unsigned int u = ((const unsigned short*)p)[i];
        return __uint_as_float(u << 16);
    }
    return ((const float*)p)[i];
}

__device__ __forceinline__ float wave_sum(float a) {
    for (int m = 1; m < 64; m <<= 1) a += __shfl_xor(a, m, 64);
    return a;
}

// round-to-nearest-even bf16 pack of (a -> low16, b -> high16)
__device__ __forceinline__ unsigned pack_bf16(float a, float b) {
    unsigned ua = __float_as_uint(a); ua = (ua + 0x7FFFu + ((ua >> 16) & 1u)) >> 16;
    unsigned ub = __float_as_uint(b); ub = (ub + 0x7FFFu + ((ub >> 16) & 1u)) >> 16;
    return ua | (ub << 16);
}

// ---------------- detection (1 block, sampled) ----------------
__global__ void detect_kernel(const void* ytrue, const void* mask, int* flags) {
    int t = threadIdx.x;
    const unsigned int* w = (const unsigned int*)ytrue;
    int nb = 0, nm = 0;
    for (int i = t; i < 16384; i += 256)
        if ((w[i] & 0xFFFFu) == 0x3F80u) nb = 1;   // bf16 1.0 at even class
    const unsigned char* mb = (const unsigned char*)mask;
    for (int i = t; i < 4096; i += 256)
        if ((i & 3) != 0 && mb[i] != 0) nm = 1;
    if (nb) atomicOr(&flags[0], 1);
    if (nm) atomicOr(&flags[1], 1);
}

// ---------------- prep: wave per node; label via ballot ----------------
__global__ void prep_kernel(const void* ytrue, const void* mask, const int* flags,
                            int* __restrict__ label, float* __restrict__ mask01) {
    int gt = blockIdx.x * blockDim.x + threadIdx.x;
    int node = gt >> 6, lane = gt & 63;
    if (node >= NN) return;
    int isbf = flags[0];
    float tv = ldf(ytrue, (long)node * CC + lane, isbf);
    unsigned long long b = __ballot(tv > 0.5f);
    if (lane == 0) {
        label[node] = (b == 0ull) ? 0 : (__ffsll((long long)b) - 1);
        int mv = flags[1] ? (int)((const unsigned char*)mask)[node] : ((const int*)mask)[node];
        mask01[node] = mv ? 1.f : 0.f;
    }
}

// ---------------- src-bucket histogram ----------------
__global__ void histS_kernel(const int* __restrict__ src, int* __restrict__ sbucket_tot) {
    __shared__ int hist[NB];
    int t = threadIdx.x;
    for (int b = t; b < NB; b += 256) hist[b] = 0;
    __syncthreads();
    int e0 = blockIdx.x * TILE;
    int n = EE - e0; if (n > TILE) n = TILE;
    for (int k = t; k < n; k += 256)
        atomicAdd(&hist[src[e0 + k] >> 8], 1);
    __syncthreads();
    for (int b = t; b < NB; b += 256)
        if (hist[b]) atomicAdd(&sbucket_tot[b], hist[b]);
}

// ---------------- exclusive scan of NB totals -> base & fill ----------------
__global__ void bscan_kernel(const int* __restrict__ tot,
                             int* __restrict__ basep, int* __restrict__ fillp) {
    int t = threadIdx.x;
    __shared__ int sm[512];
    int v = (t < NB) ? tot[t] : 0;
    sm[t] = v; __syncthreads();
    for (int off = 1; off < 512; off <<= 1) {
        int x = (t >= off) ? sm[t - off] : 0;
        __syncthreads();
        sm[t] += x;
        __syncthreads();
    }
    int ex = sm[t] - v;
    if (t <= NB) { basep[t] = ex; fillp[t] = ex; }
}

// ---------------- src binning (order within bucket irrelevant) ----------------
__global__ void __launch_bounds__(512)
binS_kernel(const int* __restrict__ src, const int* __restrict__ dst,
            int* __restrict__ sbucket_fill, uint2* __restrict__ tmp2) {
    __shared__ uint2 stage[TILE];
    __shared__ int hist[512], hofs[512], curL[512], gbase[512];
    __shared__ int sm[512];
    int t = threadIdx.x;
    int e0 = blockIdx.x * TILE;
    int n = EE - e0; if (n > TILE) n = TILE;

    hist[t] = 0;
    __syncthreads();
    for (int k = t; k < n; k += 512)
        atomicAdd(&hist[src[e0 + k] >> 8], 1);
    __syncthreads();
    int v = hist[t];
    sm[t] = v; __syncthreads();
    for (int off = 1; off < 512; off <<= 1) {
        int x = (t >= off) ? sm[t - off] : 0;
        __syncthreads();
        sm[t] += x;
        __syncthreads();
    }
    hofs[t] = sm[t] - v;
    curL[t] = sm[t] - v;
    __syncthreads();
    for (int k = t; k < n; k += 512) {
        int s = src[e0 + k], d = dst[e0 + k];
        int b = s >> 8;
        int p = atomicAdd(&curL[b], 1);
        stage[p] = make_uint2((unsigned)s, (unsigned)d);
    }
    if (t < NB) {
        int c = hist[t];
        gbase[t] = c ? atomicAdd(&sbucket_fill[t], c) : 0;
    }
    __syncthreads();
    for (int k = t; k < n; k += 512) {
        uint2 pr = stage[k];
        int b = (int)(pr.x >> 8);
        tmp2[gbase[b] + (k - hofs[b])] = pr;
    }
}

// ---------------- per-tile dst-bucket histogram (column-major tileHist[b][t]) --------
__global__ void histT_kernel(const uint2* __restrict__ tmp2, int* __restrict__ tileHist) {
    __shared__ int hist[NB];
    int t = threadIdx.x, tile = blockIdx.x;
    for (int b = t; b < NB; b += 256) hist[b] = 0;
    __syncthreads();
    int e0 = tile * TILE;
    int n = EE - e0; if (n > TILE) n = TILE;
    for (int k = t; k < n; k += 256)
        atomicAdd(&hist[tmp2[e0 + k].y >> 8], 1);
    __syncthreads();
    for (int b = t; b < NB; b += 256)
        tileHist[b * NTILE + tile] = hist[b];   // write zeros too
}

// ---------------- per-bucket exclusive scan over tiles (in place) + colsum ----------
__global__ void scanT_kernel(int* __restrict__ tileHist, int* __restrict__ colsum) {
    int t = threadIdx.x, b = blockIdx.x;
    int* col = tileHist + b * NTILE;
    __shared__ int sm[512];
    int v = (t < NTILE) ? col[t] : 0;
    sm[t] = v; __syncthreads();
    for (int off = 1; off < 512; off <<= 1) {
        int x = (t >= off) ? sm[t - off] : 0;
        __syncthreads();
        sm[t] += x;
        __syncthreads();
    }
    if (t < NTILE) col[t] = sm[t] - v;          // exclusive over tiles
    if (t == 511) colsum[b] = sm[511];
}

// ---------------- dst binning, STABLE across tiles (deterministic offsets) ----------
__global__ void __launch_bounds__(512)
binT_kernel(const uint2* __restrict__ tmp2, const int* __restrict__ bucket_base,
            const int* __restrict__ tileOfs, uint2* __restrict__ tmp) {
    __shared__ uint2 stage[TILE];
    __shared__ int hist[512], hofs[512], curL[512], gbase[512];
    __shared__ int sm[512];
    int t = threadIdx.x, tile = blockIdx.x;
    int e0 = tile * TILE;
    int n = EE - e0; if (n > TILE) n = TILE;

    hist[t] = 0;
    __syncthreads();
    for (int k = t; k < n; k += 512)
        atomicAdd(&hist[tmp2[e0 + k].y >> 8], 1);
    __syncthreads();
    int v = hist[t];
    sm[t] = v; __syncthreads();
    for (int off = 1; off < 512; off <<= 1) {
        int x = (t >= off) ? sm[t - off] : 0;
        __syncthreads();
        sm[t] += x;
        __syncthreads();
    }
    hofs[t] = sm[t] - v;
    curL[t] = sm[t] - v;
    if (t < NB) gbase[t] = bucket_base[t] + tileOfs[t * NTILE + tile];
    __syncthreads();
    // chunked staging: barrier per 512 bounds within-bucket disorder to ~1 src-bucket
    for (int k0 = 0; k0 < n; k0 += 512) {
        int k = k0 + t;
        if (k < n) {
            uint2 pr = tmp2[e0 + k];
            int b = (int)(pr.y >> 8);
            int p = atomicAdd(&curL[b], 1);
            stage[p] = pr;
        }
        __syncthreads();
    }
    for (int k = t; k < n; k += 512) {
        uint2 pr = stage[k];
        int b = (int)(pr.y >> 8);
        tmp[gbase[b] + (k - hofs[b])] = pr;
    }
}

// ---------------- per-bucket exact counting sort; emits row_ptr, norm, csr_src ------
__global__ void __launch_bounds__(256)
csrB_kernel(const uint2* __restrict__ tmp, const int* __restrict__ bucket_base,
            int* __restrict__ row_ptr, float* __restrict__ norm, int* __restrict__ csr_src) {
    __shared__ int deg[256], cur[256], sm[256];
    int t = threadIdx.x, b = blockIdx.x;
    int ebeg = bucket_base[b], eend = bucket_base[b + 1];
    deg[t] = 0;
    __syncthreads();
    for (int i = ebeg + t; i < eend; i += 256)
        atomicAdd(&deg[tmp[i].y & 255u], 1);
    __syncthreads();
    int v = deg[t];
    sm[t] = v; __syncthreads();
    for (int off = 1; off < 256; off <<= 1) {
        int x = (t >= off) ? sm[t - off] : 0;
        __syncthreads();
        sm[t] += x;
        __syncthreads();
    }
    int lofs = sm[t] - v;
    int node = b * 256 + t;
    if (node < NN) {
        row_ptr[node] = ebeg + lofs;
        int d = v; if (d < 1) d = 1;
        norm[node] = rsqrtf((float)d);
    }
    if (b == NB - 1 && t == 0) row_ptr[NN] = EE;
    cur[t] = lofs;
    __syncthreads();
    // chunked stable-ish fill: barrier per 256 keeps src-order disorder local
    for (int i0 = ebeg; i0 < eend; i0 += 256) {
        int i = i0 + t;
        if (i < eend) {
            uint2 pr = tmp[i];
            int p = atomicAdd(&cur[pr.y & 255u], 1);
            csr_src[ebeg + p] = (int)pr.x;
        }
        __syncthreads();
    }
}

// ---------------- initial error: base bf16-packed, curn bf16-packed, |e| partials ----
__global__ void err_kernel(const void* ysoft, const int* flags, const int* __restrict__ label,
                           const float* __restrict__ mask01, const float* __restrict__ norm,
                           unsigned* __restrict__ base_u, unsigned* __restrict__ curn,
                           float* __restrict__ err_part) {
    int i4 = blockIdx.x * 256 + threadIdx.x;     // float4 index
    int node = i4 >> 4;
    int isbf = flags[0];
    float m = mask01[node];
    int lab = label[node];
    float nrm = norm[node];
    int c0 = (i4 & 15) * 4;
    float4 e;
    if (isbf) {
        ushort4 u = ((const ushort4*)ysoft)[i4];
        e.x = __uint_as_float((unsigned)u.x << 16);
        e.y = __uint_as_float((unsigned)u.y << 16);
        e.z = __uint_as_float((unsigned)u.z << 16);
        e.w = __uint_as_float((unsigned)u.w << 16);
    } else {
        e = ((const float4*)ysoft)[i4];
    }
    e.x = (m != 0.f) ? ((c0 + 0 == lab) ? 1.f : 0.f) - e.x : 0.f;
    e.y = (m != 0.f) ? ((c0 + 1 == lab) ? 1.f : 0.f) - e.y : 0.f;
    e.z = (m != 0.f) ? ((c0 + 2 == lab) ? 1.f : 0.f) - e.z : 0.f;
    e.w = (m != 0.f) ? ((c0 + 3 == lab) ? 1.f : 0.f) - e.w : 0.f;
    ((uint2*)base_u)[i4] = make_uint2(pack_bf16(e.x, e.y), pack_bf16(e.z, e.w));
    ((uint2*)curn)[i4] = make_uint2(pack_bf16(e.x * nrm, e.y * nrm),
                                    pack_bf16(e.z * nrm, e.w * nrm));
    float a = fabsf(e.x) + fabsf(e.y) + fabsf(e.z) + fabsf(e.w);
    a = wave_sum(a);
    __shared__ float sm[4];
    if ((threadIdx.x & 63) == 0) sm[threadIdx.x >> 6] = a;
    __syncthreads();
    if (threadIdx.x == 0) err_part[blockIdx.x] = sm[0] + sm[1] + sm[2] + sm[3];
}

// ---------------- single-block reduce: scal[0]=numel, scal[1]=sum|err| ----------------
__global__ void reduce_kernel(const float* __restrict__ mask01,
                              const float* __restrict__ err_part, float* __restrict__ scal) {
    int t = threadIdx.x;
    float s0 = 0.f, s1 = 0.f;
    for (int i = t; i < NN; i += 1024) s0 += mask01[i];
    for (int i = t; i < ERR_BLOCKS; i += 1024) s1 += err_part[i];
    __shared__ float a0[1024], a1[1024];
    a0[t] = s0; a1[t] = s1; __syncthreads();
    for (int s = 512; s > 0; s >>= 1) {
        if (t < s) { a0[t] += a0[t + s]; a1[t] += a1[t + s]; }
        __syncthreads();
    }
    if (t == 0) { scal[0] = a0[0]; scal[1] = a1[0]; }
}

// ---------------- pull-gather, bf16 state + bf16 base ----------------
// mode 0: store pack_bf16(v*nrm) -> next curn
// mode 1: store fp32 v (float2, standard layout) + rowsum[node]=sum|v|
// mode 3: final -> d_out per dtype flag
__global__ void gather_kernel(const int* __restrict__ row_ptr, const int* __restrict__ csr_src,
                              const unsigned* __restrict__ curn, const unsigned* __restrict__ base_u,
                              const float* __restrict__ norm, void* __restrict__ out,
                              float* __restrict__ rowsum, const int* flags,
                              float alpha, float lo, float hi, int mode) {
    int gt = blockIdx.x * blockDim.x + threadIdx.x;
    int node = gt >> 6, lane = gt & 63;
    if (node >= NN) return;
    int hl = lane & 31;          // half-lane: class pair index
    int half = lane >> 5;        // 0 -> even edge, 1 -> odd edge
    int beg = row_ptr[node], end = row_ptr[node + 1];

    // hoist epilogue loads ahead of the gather loop
    float nrm = norm[node];
    long i2 = (long)node * 32 + hl;
    unsigned bu = __builtin_nontemporal_load(base_u + i2);
    float b0 = __uint_as_float(bu << 16);
    float b1 = __uint_as_float(bu & 0xFFFF0000u);

    float acc0 = 0.f, acc1 = 0.f, acc2 = 0.f, acc3 = 0.f;
    for (int eb = beg; eb < end; eb += 64) {
        int ne = end - eb; if (ne > 64) ne = 64;
        int sv = (eb + lane < end) ? __builtin_nontemporal_load(csr_src + eb + lane) : 0;
        int j = 0;
        for (; j + 15 < ne; j += 16) {
            int s0 = __shfl(sv, j + 0  + half, 64);
            int s1 = __shfl(sv, j + 2  + half, 64);
            int s2 = __shfl(sv, j + 4  + half, 64);
            int s3 = __shfl(sv, j + 6  + half, 64);
            int s4 = __shfl(sv, j + 8  + half, 64);
            int s5 = __shfl(sv, j + 10 + half, 64);
            int s6 = __shfl(sv, j + 12 + half, 64);
            int s7 = __shfl(sv, j + 14 + half, 64);
            unsigned w0 = curn[(long)s0 * 32 + hl];
            unsigned w1 = curn[(long)s1 * 32 + hl];
            unsigned w2 = curn[(long)s2 * 32 + hl];
            unsigned w3 = curn[(long)s3 * 32 + hl];
            unsigned w4 = curn[(long)s4 * 32 + hl];
            unsigned w5 = curn[(long)s5 * 32 + hl];
            unsigned w6 = curn[(long)s6 * 32 + hl];
            unsigned w7 = curn[(long)s7 * 32 + hl];
            acc0 += __uint_as_float(w0 << 16) + __uint_as_float(w2 << 16)
                  + __uint_as_float(w4 << 16) + __uint_as_float(w6 << 16);
            acc1 += __uint_as_float(w0 & 0xFFFF0000u) + __uint_as_float(w2 & 0xFFFF0000u)
                  + __uint_as_float(w4 & 0xFFFF0000u) + __uint_as_float(w6 & 0xFFFF0000u);
            acc2 += __uint_as_float(w1 << 16) + __uint_as_float(w3 << 16)
                  + __uint_as_float(w5 << 16) + __uint_as_float(w7 << 16);
            acc3 += __uint_as_float(w1 & 0xFFFF0000u) + __uint_as_float(w3 & 0xFFFF0000u)
                  + __uint_as_float(w5 & 0xFFFF0000u) + __uint_as_float(w7 & 0xFFFF0000u);
        }
        for (; j + 7 < ne; j += 8) {
            int s0 = __shfl(sv, j + 0 + half, 64);
            int s1 = __shfl(sv, j + 2 + half, 64);
            int s2 = __shfl(sv, j + 4 + half, 64);
            int s3 = __shfl(sv, j + 6 + half, 64);
            unsigned w0 = curn[(long)s0 * 32 + hl];
            unsigned w1 = curn[(long)s1 * 32 + hl];
            unsigned w2 = curn[(long)s2 * 32 + hl];
            unsigned w3 = curn[(long)s3 * 32 + hl];
            acc0 += __uint_as_float(w0 << 16) + __uint_as_float(w2 << 16);
            acc1 += __uint_as_float(w0 & 0xFFFF0000u) + __uint_as_float(w2 & 0xFFFF0000u);
            acc2 += __uint_as_float(w1 << 16) + __uint_as_float(w3 << 16);
            acc3 += __uint_as_float(w1 & 0xFFFF0000u) + __uint_as_float(w3 & 0xFFFF0000u);
        }
        for (; j < ne; j += 2) {
            int jj = j + half;
            float wt = (jj < ne) ? 1.f : 0.f;
            int s = __shfl(sv, (jj < ne) ? jj : j, 64);
            unsigned w = curn[(long)s * 32 + hl];
            acc0 += wt * __uint_as_float(w << 16);
            acc1 += wt * __uint_as_float(w & 0xFFFF0000u);
        }
    }
    acc0 += acc2; acc1 += acc3;
    acc0 += __shfl_xor(acc0, 32, 64);
    acc1 += __shfl_xor(acc1, 32, 64);

    float v0 = (1.f - alpha) * b0 + alpha * nrm * acc0;
    float v1 = (1.f - alpha) * b1 + alpha * nrm * acc1;
    v0 = v0 < lo ? lo : (v0 > hi ? hi : v0);
    v1 = v1 < lo ? lo : (v1 > hi ? hi : v1);

    if (mode == 1) {
        float contrib = (lane < 32) ? (fabsf(v0) + fabsf(v1)) : 0.f;
        float rs = wave_sum(contrib);
        if (lane == 0) rowsum[node] = rs;
        if (lane < 32) {
            float* op = (float*)out + i2 * 2;
            __builtin_nontemporal_store(v0, op);
            __builtin_nontemporal_store(v1, op + 1);
        }
    } else if (mode == 0) {
        if (lane < 32)
            __builtin_nontemporal_store(pack_bf16(v0 * nrm, v1 * nrm), (unsigned*)out + i2);
    } else {
        if (lane < 32) {
            if (flags[0]) __builtin_nontemporal_store(pack_bf16(v0, v1), (unsigned*)out + i2);
            else {
                float* op = (float*)out + i2 * 2;
                __builtin_nontemporal_store(v0, op);
                __builtin_nontemporal_store(v1, op + 1);
            }
        }
    }
}

// ---------------- y0 (fused scale): base_u=bf16(y0), curn=bf16(y0*norm) ----------------
__global__ void y0_kernel(const void* ysoft, const int* flags, const int* __restrict__ label,
                          const float* __restrict__ mask01, const float* __restrict__ rowsum,
                          const float* __restrict__ scal,
                          const float* __restrict__ norm, const float* __restrict__ smoothed,
                          unsigned* __restrict__ base_u, unsigned* __restrict__ curn) {
    int i4 = blockIdx.x * 256 + threadIdx.x;
    int node = i4 >> 4;
    int isbf = flags[0];
    float m = mask01[node];
    int lab = label[node];
    float nrm = norm[node];
    float sigma = scal[1] / scal[0];
    float sc = sigma / rowsum[node];
    if (isinf(sc) || sc > 1000.f) sc = 1.f;  // NaN falls through (matches ref)
    int c0 = (i4 & 15) * 4;
    float4 ys;
    if (isbf) {
        ushort4 u = ((const ushort4*)ysoft)[i4];
        ys.x = __uint_as_float((unsigned)u.x << 16);
        ys.y = __uint_as_float((unsigned)u.y << 16);
        ys.z = __uint_as_float((unsigned)u.z << 16);
        ys.w = __uint_as_float((unsigned)u.w << 16);
    } else {
        ys = ((const float4*)ysoft)[i4];
    }
    float4 sm = ((const float4*)smoothed)[i4];
    float rx = ys.x + sc * sm.x; if (isnan(rx)) rx = ys.x;
    float ry = ys.y + sc * sm.y; if (isnan(ry)) ry = ys.y;
    float rz = ys.z + sc * sm.z; if (isnan(rz)) rz = ys.z;
    float rw = ys.w + sc * sm.w; if (isnan(rw)) rw = ys.w;
    float4 y;
    y.x = (m != 0.f) ? ((c0 + 0 == lab) ? 1.f : 0.f) : rx;
    y.y = (m != 0.f) ? ((c0 + 1 == lab) ? 1.f : 0.f) : ry;
    y.z = (m != 0.f) ? ((c0 + 2 == lab) ? 1.f : 0.f) : rz;
    y.w = (m != 0.f) ? ((c0 + 3 == lab) ? 1.f : 0.f) : rw;
    ((uint2*)base_u)[i4] = make_uint2(pack_bf16(y.x, y.y), pack_bf16(y.z, y.w));
    ((uint2*)curn)[i4] = make_uint2(pack_bf16(y.x * nrm, y.y * nrm),
                                    pack_bf16(y.z * nrm, y.w * nrm));
}

extern "C" void kernel_launch(void* const* d_in, const int* in_sizes, int n_in,
                              void* d_out, int out_size, void* d_ws, size_t ws_size,
                              hipStream_t stream) {
    const void* ysoft = d_in[0];
    const void* ytrue = d_in[1];
    const int* src = (const int*)d_in[2];
    const int* dst = (const int*)d_in[3];
    const void* mask = d_in[4];

    char* ws = (char*)d_ws;
    // ---- zeroed region [0, 8192) ----
    int*   flags        = (int*)ws;
    float* scal         = (float*)(ws + 64);
    int*   sbucket_tot  = (int*)(ws + 4096);         // NB ints (zeroed)
    size_t ZERO_BYTES   = 8192;
    int*   sbucket_base = (int*)(ws + 8192);         // NB+1 (written by bscan)
    int*   sbucket_fill = (int*)(ws + 12288);
    int*   bucket_base  = (int*)(ws + 16384);
    int*   bucket_fill  = (int*)(ws + 20480);
    int*   colsum       = (int*)(ws + 24576);        // NB ints (written by scanT)
    float* err_part     = (float*)(ws + 28672);      // ERR_BLOCKS floats (25 KB)

    size_t off = 28672 + (size_t)ERR_BLOCKS * 4;
    off = (off + 255) & ~(size_t)255;
    int*   tileHist = (int*)(ws + off);  off += (size_t)NB * NTILE * 4;   // 611 KB
    off = (off + 255) & ~(size_t)255;
    int*   label   = (int*)(ws + off);   off += (size_t)NN * 4;
    float* mask01  = (float*)(ws + off); off += (size_t)NN * 4;
    float* norm    = (float*)(ws + off); off += (size_t)NN * 4;
    float* rowsum  = (float*)(ws + off); off += (size_t)NN * 4;
    int*   row_ptr = (int*)(ws + off);   off += (size_t)(NN + 1) * 4;
    off = (off + 255) & ~(size_t)255;
    int*   csr_src = (int*)(ws + off);   off += (size_t)EE * 4;
    off = (off + 255) & ~(size_t)255;
    unsigned* base_u   = (unsigned*)(ws + off); off += (size_t)NC * 2;    // bf16 packed
    unsigned* bufA     = (unsigned*)(ws + off); off += (size_t)NC * 2;
    unsigned* bufB     = (unsigned*)(ws + off); off += (size_t)NC * 2;
    float*    smoothed = (float*)(ws + off);    off += (size_t)NC * 4;
    // tmp  (EE uint2 = 25.6 MB) aliases [base_u, bufA+...): dead before err_kernel
    uint2* tmp  = (uint2*)base_u;
    // tmp2 (EE uint2 = 25.6 MB) aliases smoothed: dead before last correct gather
    uint2* tmp2 = (uint2*)smoothed;

    hipMemsetAsync(ws, 0, ZERO_BYTES, stream);

    detect_kernel<<<1, 256, 0, stream>>>(ytrue, mask, flags);
    prep_kernel<<<(NN * 64 + 255) / 256, 256, 0, stream>>>(ytrue, mask, flags, label, mask01);
    // ---- src-sort pass (coarse 256-node buckets) ----
    histS_kernel<<<NTILE, 256, 0, stream>>>(src, sbucket_tot);
    bscan_kernel<<<1, 512, 0, stream>>>(sbucket_tot, sbucket_base, sbucket_fill);
    binS_kernel<<<NTILE, 512, 0, stream>>>(src, dst, sbucket_fill, tmp2);
    // ---- dst-CSR build, stable w.r.t. src order ----
    histT_kernel<<<NTILE, 256, 0, stream>>>(tmp2, tileHist);
    scanT_kernel<<<NB, 512, 0, stream>>>(tileHist, colsum);
    bscan_kernel<<<1, 512, 0, stream>>>(colsum, bucket_base, bucket_fill);
    binT_kernel<<<NTILE, 512, 0, stream>>>(tmp2, bucket_base, tileHist, tmp);
    csrB_kernel<<<NB, 256, 0, stream>>>(tmp, bucket_base, row_ptr, norm, csr_src);
    // ---- initial error ----
    err_kernel<<<ERR_BLOCKS, 256, 0, stream>>>(ysoft, flags, label, mask01, norm, base_u, bufA, err_part);
    reduce_kernel<<<1, 1024, 0, stream>>>(mask01, err_part, scal);

    const int gather_blocks = (NN * 64 + 255) / 256;

    // ---- correct phase: 10 layers, alpha=0.979, clip [-1,1]
    unsigned* cur = bufA; unsigned* nxt = bufB;
    for (int l = 0; l < 10; l++) {
        int mode = (l < 9) ? 0 : 1;
        void* o = (l < 9) ? (void*)nxt : (void*)smoothed;
        gather_kernel<<<gather_blocks, 256, 0, stream>>>(row_ptr, csr_src, cur, base_u, norm, o,
                                                         rowsum, flags, 0.979f, -1.f, 1.f, mode);
        unsigned* t = cur; cur = nxt; nxt = t;
    }

    y0_kernel<<<ERR_BLOCKS, 256, 0, stream>>>(ysoft, flags, label, mask01, rowsum, scal, norm,
                                              smoothed, base_u, bufA);

    // ---- smooth phase: 10 layers, alpha=0.756, clip [0,1]; last writes d_out
    cur = bufA; nxt = bufB;
    for (int l = 0; l < 10; l++) {
        int mode = (l < 9) ? 0 : 3;
        void* o = (l < 9) ? (void*)nxt : (void*)d_out;
        gather_kernel<<<gather_blocks, 256, 0, stream>>>(row_ptr, csr_src, cur, base_u, norm, o,
                                                         rowsum, flags, 0.756f, 0.f, 1.f, mode);
        unsigned* t = cur; cur = nxt; nxt = t;
    }
}

// Round 9
// 1434.026 us; speedup vs baseline: 1.0231x; 1.0231x over previous
//
#include <hip/hip_runtime.h>
#include <hip/hip_bf16.h>

#define NN 100000
#define EE 3200000
#define CC 64
#define NC (NN*CC)
#define ERR_BLOCKS 6250        // NC/4/256
#define NB 391                 // buckets = dst>>8, ceil(NN/256)
#define TILE 8192              // edges per binning block
#define NTILE 391              // ceil(EE/TILE)

// ---------------- helpers ----------------
__device__ __forceinline__ float ldf(const void* p, long i, int isbf) {
    if (isbf) {
        unsigned int u = ((const unsigned short*)p)[i];
        return __uint_as_float(u << 16);
    }
    return ((const float*)p)[i];
}

__device__ __forceinline__ float wave_sum(float a) {
    for (int m = 1; m < 64; m <<= 1) a += __shfl_xor(a, m, 64);
    return a;
}

// round-to-nearest-even bf16 pack of (a -> low16, b -> high16)
__device__ __forceinline__ unsigned pack_bf16(float a, float b) {
    unsigned ua = __float_as_uint(a); ua = (ua + 0x7FFFu + ((ua >> 16) & 1u)) >> 16;
    unsigned ub = __float_as_uint(b); ub = (ub + 0x7FFFu + ((ub >> 16) & 1u)) >> 16;
    return ua | (ub << 16);
}

// ---------------- detection (1 block, sampled) ----------------
__global__ void detect_kernel(const void* ytrue, const void* mask, int* flags) {
    int t = threadIdx.x;
    const unsigned int* w = (const unsigned int*)ytrue;
    int nb = 0, nm = 0;
    for (int i = t; i < 16384; i += 256)
        if ((w[i] & 0xFFFFu) == 0x3F80u) nb = 1;   // bf16 1.0 at even class
    const unsigned char* mb = (const unsigned char*)mask;
    for (int i = t; i < 4096; i += 256)
        if ((i & 3) != 0 && mb[i] != 0) nm = 1;
    if (nb) atomicOr(&flags[0], 1);
    if (nm) atomicOr(&flags[1], 1);
}

// ---------------- prep: wave per node; label via ballot ----------------
__global__ void prep_kernel(const void* ytrue, const void* mask, const int* flags,
                            int* __restrict__ label, float* __restrict__ mask01) {
    int gt = blockIdx.x * blockDim.x + threadIdx.x;
    int node = gt >> 6, lane = gt & 63;
    if (node >= NN) return;
    int isbf = flags[0];
    float tv = ldf(ytrue, (long)node * CC + lane, isbf);
    unsigned long long b = __ballot(tv > 0.5f);
    if (lane == 0) {
        label[node] = (b == 0ull) ? 0 : (__ffsll((long long)b) - 1);
        int mv = flags[1] ? (int)((const unsigned char*)mask)[node] : ((const int*)mask)[node];
        mask01[node] = mv ? 1.f : 0.f;
    }
}

// ---------------- dst-bucket histogram (LDS-aggregated) ----------------
__global__ void histA_kernel(const int* __restrict__ dst, int* __restrict__ bucket_tot) {
    __shared__ int hist[NB];
    int t = threadIdx.x;
    for (int b = t; b < NB; b += 256) hist[b] = 0;
    __syncthreads();
    int e0 = blockIdx.x * TILE;
    int n = EE - e0; if (n > TILE) n = TILE;
    for (int k = t; k < n; k += 256)
        atomicAdd(&hist[dst[e0 + k] >> 8], 1);
    __syncthreads();
    for (int b = t; b < NB; b += 256)
        if (hist[b]) atomicAdd(&bucket_tot[b], hist[b]);
}

// ---------------- exclusive scan of NB totals -> base & fill ----------------
__global__ void bscan_kernel(const int* __restrict__ tot,
                             int* __restrict__ basep, int* __restrict__ fillp) {
    int t = threadIdx.x;
    __shared__ int sm[512];
    int v = (t < NB) ? tot[t] : 0;
    sm[t] = v; __syncthreads();
    for (int off = 1; off < 512; off <<= 1) {
        int x = (t >= off) ? sm[t - off] : 0;
        __syncthreads();
        sm[t] += x;
        __syncthreads();
    }
    int ex = sm[t] - v;
    if (t <= NB) { basep[t] = ex; fillp[t] = ex; }
}

// ---------------- binning: LDS-stage a tile grouped by bucket, write runs ------------
__global__ void __launch_bounds__(512)
binA_kernel(const int* __restrict__ src, const int* __restrict__ dst,
            int* __restrict__ bucket_fill, uint2* __restrict__ tmp) {
    __shared__ uint2 stage[TILE];
    __shared__ int hist[512], hofs[512], curL[512], gbase[512];
    __shared__ int sm[512];
    int t = threadIdx.x;
    int e0 = blockIdx.x * TILE;
    int n = EE - e0; if (n > TILE) n = TILE;

    hist[t] = 0;
    __syncthreads();
    for (int k = t; k < n; k += 512)
        atomicAdd(&hist[dst[e0 + k] >> 8], 1);
    __syncthreads();
    int v = hist[t];
    sm[t] = v; __syncthreads();
    for (int off = 1; off < 512; off <<= 1) {
        int x = (t >= off) ? sm[t - off] : 0;
        __syncthreads();
        sm[t] += x;
        __syncthreads();
    }
    hofs[t] = sm[t] - v;
    curL[t] = sm[t] - v;
    __syncthreads();
    for (int k = t; k < n; k += 512) {
        int s = src[e0 + k], d = dst[e0 + k];
        int b = d >> 8;
        int p = atomicAdd(&curL[b], 1);
        stage[p] = make_uint2((unsigned)s, (unsigned)d);
    }
    if (t < NB) {
        int c = hist[t];
        gbase[t] = c ? atomicAdd(&bucket_fill[t], c) : 0;
    }
    __syncthreads();
    for (int k = t; k < n; k += 512) {
        uint2 pr = stage[k];
        int b = (int)(pr.y >> 8);
        tmp[gbase[b] + (k - hofs[b])] = pr;
    }
}

// ---------------- per-bucket exact counting sort; emits row_ptr, norm, csr_src ------
__global__ void __launch_bounds__(256)
csrB_kernel(const uint2* __restrict__ tmp, const int* __restrict__ bucket_base,
            int* __restrict__ row_ptr, float* __restrict__ norm, int* __restrict__ csr_src) {
    __shared__ int deg[256], cur[256], sm[256];
    int t = threadIdx.x, b = blockIdx.x;
    int ebeg = bucket_base[b], eend = bucket_base[b + 1];
    deg[t] = 0;
    __syncthreads();
    for (int i = ebeg + t; i < eend; i += 256)
        atomicAdd(&deg[tmp[i].y & 255u], 1);
    __syncthreads();
    int v = deg[t];
    sm[t] = v; __syncthreads();
    for (int off = 1; off < 256; off <<= 1) {
        int x = (t >= off) ? sm[t - off] : 0;
        __syncthreads();
        sm[t] += x;
        __syncthreads();
    }
    int lofs = sm[t] - v;
    int node = b * 256 + t;
    if (node < NN) {
        row_ptr[node] = ebeg + lofs;
        int d = v; if (d < 1) d = 1;
        norm[node] = rsqrtf((float)d);
    }
    if (b == NB - 1 && t == 0) row_ptr[NN] = EE;
    cur[t] = lofs;
    __syncthreads();
    for (int i = ebeg + t; i < eend; i += 256) {
        uint2 pr = tmp[i];
        int p = atomicAdd(&cur[pr.y & 255u], 1);
        csr_src[ebeg + p] = (int)pr.x;
    }
}

// ---------------- initial error: base bf16-packed, curn bf16-packed, |e| partials ----
__global__ void err_kernel(const void* ysoft, const int* flags, const int* __restrict__ label,
                           const float* __restrict__ mask01, const float* __restrict__ norm,
                           unsigned* __restrict__ base_u, unsigned* __restrict__ curn,
                           float* __restrict__ err_part) {
    int i4 = blockIdx.x * 256 + threadIdx.x;     // float4 index
    int node = i4 >> 4;
    int isbf = flags[0];
    float m = mask01[node];
    int lab = label[node];
    float nrm = norm[node];
    int c0 = (i4 & 15) * 4;
    float4 e;
    if (isbf) {
        ushort4 u = ((const ushort4*)ysoft)[i4];
        e.x = __uint_as_float((unsigned)u.x << 16);
        e.y = __uint_as_float((unsigned)u.y << 16);
        e.z = __uint_as_float((unsigned)u.z << 16);
        e.w = __uint_as_float((unsigned)u.w << 16);
    } else {
        e = ((const float4*)ysoft)[i4];
    }
    e.x = (m != 0.f) ? ((c0 + 0 == lab) ? 1.f : 0.f) - e.x : 0.f;
    e.y = (m != 0.f) ? ((c0 + 1 == lab) ? 1.f : 0.f) - e.y : 0.f;
    e.z = (m != 0.f) ? ((c0 + 2 == lab) ? 1.f : 0.f) - e.z : 0.f;
    e.w = (m != 0.f) ? ((c0 + 3 == lab) ? 1.f : 0.f) - e.w : 0.f;
    ((uint2*)base_u)[i4] = make_uint2(pack_bf16(e.x, e.y), pack_bf16(e.z, e.w));
    ((uint2*)curn)[i4] = make_uint2(pack_bf16(e.x * nrm, e.y * nrm),
                                    pack_bf16(e.z * nrm, e.w * nrm));
    float a = fabsf(e.x) + fabsf(e.y) + fabsf(e.z) + fabsf(e.w);
    a = wave_sum(a);
    __shared__ float sm[4];
    if ((threadIdx.x & 63) == 0) sm[threadIdx.x >> 6] = a;
    __syncthreads();
    if (threadIdx.x == 0) err_part[blockIdx.x] = sm[0] + sm[1] + sm[2] + sm[3];
}

// ---------------- single-block reduce: scal[0]=numel, scal[1]=sum|err| ----------------
__global__ void reduce_kernel(const float* __restrict__ mask01,
                              const float* __restrict__ err_part, float* __restrict__ scal) {
    int t = threadIdx.x;
    float s0 = 0.f, s1 = 0.f;
    for (int i = t; i < NN; i += 1024) s0 += mask01[i];
    for (int i = t; i < ERR_BLOCKS; i += 1024) s1 += err_part[i];
    __shared__ float a0[1024], a1[1024];
    a0[t] = s0; a1[t] = s1; __syncthreads();
    for (int s = 512; s > 0; s >>= 1) {
        if (t < s) { a0[t] += a0[t + s]; a1[t] += a1[t + s]; }
        __syncthreads();
    }
    if (t == 0) { scal[0] = a0[0]; scal[1] = a1[0]; }
}

// ---------------- pull-gather, bf16 state + bf16 base ----------------
// mode 0: store pack_bf16(v*nrm) -> next curn  (normal store: stays in writer XCD L2)
// mode 1: store fp32 v (float2) + rowsum[node]=sum|v|
// mode 3: final -> d_out per dtype flag
__global__ void gather_kernel(const int* __restrict__ row_ptr, const int* __restrict__ csr_src,
                              const unsigned* __restrict__ curn, const unsigned* __restrict__ base_u,
                              const float* __restrict__ norm, void* __restrict__ out,
                              float* __restrict__ rowsum, const int* flags,
                              float alpha, float lo, float hi, int mode) {
    int gt = blockIdx.x * blockDim.x + threadIdx.x;
    int node = gt >> 6, lane = gt & 63;
    if (node >= NN) return;
    int hl = lane & 31;          // half-lane: class pair index
    int half = lane >> 5;        // 0 -> even edge, 1 -> odd edge
    int beg = row_ptr[node], end = row_ptr[node + 1];

    // hoist epilogue loads ahead of the gather loop
    float nrm = norm[node];
    long i2 = (long)node * 32 + hl;
    unsigned bu = __builtin_nontemporal_load(base_u + i2);   // streamed: don't evict curn
    float b0 = __uint_as_float(bu << 16);
    float b1 = __uint_as_float(bu & 0xFFFF0000u);

    float acc0 = 0.f, acc1 = 0.f, acc2 = 0.f, acc3 = 0.f;
    for (int eb = beg; eb < end; eb += 64) {
        int ne = end - eb; if (ne > 64) ne = 64;
        int sv = (eb + lane < end) ? __builtin_nontemporal_load(csr_src + eb + lane) : 0;
        int j = 0;
        for (; j + 15 < ne; j += 16) {
            int s0 = __shfl(sv, j + 0  + half, 64);
            int s1 = __shfl(sv, j + 2  + half, 64);
            int s2 = __shfl(sv, j + 4  + half, 64);
            int s3 = __shfl(sv, j + 6  + half, 64);
            int s4 = __shfl(sv, j + 8  + half, 64);
            int s5 = __shfl(sv, j + 10 + half, 64);
            int s6 = __shfl(sv, j + 12 + half, 64);
            int s7 = __shfl(sv, j + 14 + half, 64);
            unsigned w0 = curn[(long)s0 * 32 + hl];
            unsigned w1 = curn[(long)s1 * 32 + hl];
            unsigned w2 = curn[(long)s2 * 32 + hl];
            unsigned w3 = curn[(long)s3 * 32 + hl];
            unsigned w4 = curn[(long)s4 * 32 + hl];
            unsigned w5 = curn[(long)s5 * 32 + hl];
            unsigned w6 = curn[(long)s6 * 32 + hl];
            unsigned w7 = curn[(long)s7 * 32 + hl];
            acc0 += __uint_as_float(w0 << 16) + __uint_as_float(w2 << 16)
                  + __uint_as_float(w4 << 16) + __uint_as_float(w6 << 16);
            acc1 += __uint_as_float(w0 & 0xFFFF0000u) + __uint_as_float(w2 & 0xFFFF0000u)
                  + __uint_as_float(w4 & 0xFFFF0000u) + __uint_as_float(w6 & 0xFFFF0000u);
            acc2 += __uint_as_float(w1 << 16) + __uint_as_float(w3 << 16)
                  + __uint_as_float(w5 << 16) + __uint_as_float(w7 << 16);
            acc3 += __uint_as_float(w1 & 0xFFFF0000u) + __uint_as_float(w3 & 0xFFFF0000u)
                  + __uint_as_float(w5 & 0xFFFF0000u) + __uint_as_float(w7 & 0xFFFF0000u);
        }
        for (; j + 7 < ne; j += 8) {
            int s0 = __shfl(sv, j + 0 + half, 64);
            int s1 = __shfl(sv, j + 2 + half, 64);
            int s2 = __shfl(sv, j + 4 + half, 64);
            int s3 = __shfl(sv, j + 6 + half, 64);
            unsigned w0 = curn[(long)s0 * 32 + hl];
            unsigned w1 = curn[(long)s1 * 32 + hl];
            unsigned w2 = curn[(long)s2 * 32 + hl];
            unsigned w3 = curn[(long)s3 * 32 + hl];
            acc0 += __uint_as_float(w0 << 16) + __uint_as_float(w2 << 16);
            acc1 += __uint_as_float(w0 & 0xFFFF0000u) + __uint_as_float(w2 & 0xFFFF0000u);
            acc2 += __uint_as_float(w1 << 16) + __uint_as_float(w3 << 16);
            acc3 += __uint_as_float(w1 & 0xFFFF0000u) + __uint_as_float(w3 & 0xFFFF0000u);
        }
        for (; j < ne; j += 2) {
            int jj = j + half;
            float wt = (jj < ne) ? 1.f : 0.f;
            int s = __shfl(sv, (jj < ne) ? jj : j, 64);
            unsigned w = curn[(long)s * 32 + hl];
            acc0 += wt * __uint_as_float(w << 16);
            acc1 += wt * __uint_as_float(w & 0xFFFF0000u);
        }
    }
    acc0 += acc2; acc1 += acc3;
    acc0 += __shfl_xor(acc0, 32, 64);
    acc1 += __shfl_xor(acc1, 32, 64);

    float v0 = (1.f - alpha) * b0 + alpha * nrm * acc0;
    float v1 = (1.f - alpha) * b1 + alpha * nrm * acc1;
    v0 = v0 < lo ? lo : (v0 > hi ? hi : v0);
    v1 = v1 < lo ? lo : (v1 > hi ? hi : v1);

    if (mode == 1) {
        float contrib = (lane < 32) ? (fabsf(v0) + fabsf(v1)) : 0.f;
        float rs = wave_sum(contrib);
        if (lane == 0) rowsum[node] = rs;
        if (lane < 32) {
            float* op = (float*)out + i2 * 2;
            __builtin_nontemporal_store(v0, op);
            __builtin_nontemporal_store(v1, op + 1);
        }
    } else if (mode == 0) {
        if (lane < 32) ((unsigned*)out)[i2] = pack_bf16(v0 * nrm, v1 * nrm);
    } else {
        if (lane < 32) {
            if (flags[0]) __builtin_nontemporal_store(pack_bf16(v0, v1), (unsigned*)out + i2);
            else {
                float* op = (float*)out + i2 * 2;
                __builtin_nontemporal_store(v0, op);
                __builtin_nontemporal_store(v1, op + 1);
            }
        }
    }
}

// ---------------- y0 (fused scale): base_u=bf16(y0), curn=bf16(y0*norm) ----------------
__global__ void y0_kernel(const void* ysoft, const int* flags, const int* __restrict__ label,
                          const float* __restrict__ mask01, const float* __restrict__ rowsum,
                          const float* __restrict__ scal,
                          const float* __restrict__ norm, const float* __restrict__ smoothed,
                          unsigned* __restrict__ base_u, unsigned* __restrict__ curn) {
    int i4 = blockIdx.x * 256 + threadIdx.x;
    int node = i4 >> 4;
    int isbf = flags[0];
    float m = mask01[node];
    int lab = label[node];
    float nrm = norm[node];
    float sigma = scal[1] / scal[0];
    float sc = sigma / rowsum[node];
    if (isinf(sc) || sc > 1000.f) sc = 1.f;  // NaN falls through (matches ref)
    int c0 = (i4 & 15) * 4;
    float4 ys;
    if (isbf) {
        ushort4 u = ((const ushort4*)ysoft)[i4];
        ys.x = __uint_as_float((unsigned)u.x << 16);
        ys.y = __uint_as_float((unsigned)u.y << 16);
        ys.z = __uint_as_float((unsigned)u.z << 16);
        ys.w = __uint_as_float((unsigned)u.w << 16);
    } else {
        ys = ((const float4*)ysoft)[i4];
    }
    float4 sm = ((const float4*)smoothed)[i4];
    float rx = ys.x + sc * sm.x; if (isnan(rx)) rx = ys.x;
    float ry = ys.y + sc * sm.y; if (isnan(ry)) ry = ys.y;
    float rz = ys.z + sc * sm.z; if (isnan(rz)) rz = ys.z;
    float rw = ys.w + sc * sm.w; if (isnan(rw)) rw = ys.w;
    float4 y;
    y.x = (m != 0.f) ? ((c0 + 0 == lab) ? 1.f : 0.f) : rx;
    y.y = (m != 0.f) ? ((c0 + 1 == lab) ? 1.f : 0.f) : ry;
    y.z = (m != 0.f) ? ((c0 + 2 == lab) ? 1.f : 0.f) : rz;
    y.w = (m != 0.f) ? ((c0 + 3 == lab) ? 1.f : 0.f) : rw;
    ((uint2*)base_u)[i4] = make_uint2(pack_bf16(y.x, y.y), pack_bf16(y.z, y.w));
    ((uint2*)curn)[i4] = make_uint2(pack_bf16(y.x * nrm, y.y * nrm),
                                    pack_bf16(y.z * nrm, y.w * nrm));
}

extern "C" void kernel_launch(void* const* d_in, const int* in_sizes, int n_in,
                              void* d_out, int out_size, void* d_ws, size_t ws_size,
                              hipStream_t stream) {
    const void* ysoft = d_in[0];
    const void* ytrue = d_in[1];
    const int* src = (const int*)d_in[2];
    const int* dst = (const int*)d_in[3];
    const void* mask = d_in[4];

    char* ws = (char*)d_ws;
    // ---- zeroed region [0, 8192) ----
    int*   flags       = (int*)ws;
    float* scal        = (float*)(ws + 64);
    int*   bucket_tot  = (int*)(ws + 4096);          // NB ints (zeroed)
    size_t ZERO_BYTES  = 8192;
    int*   bucket_base = (int*)(ws + 8192);          // NB+1 (written by bscan)
    int*   bucket_fill = (int*)(ws + 12288);
    float* err_part    = (float*)(ws + 16384);       // ERR_BLOCKS floats (25 KB)

    size_t off = 16384 + (size_t)ERR_BLOCKS * 4;
    off = (off + 255) & ~(size_t)255;
    int*   label   = (int*)(ws + off);   off += (size_t)NN * 4;
    float* mask01  = (float*)(ws + off); off += (size_t)NN * 4;
    float* norm    = (float*)(ws + off); off += (size_t)NN * 4;
    float* rowsum  = (float*)(ws + off); off += (size_t)NN * 4;
    int*   row_ptr = (int*)(ws + off);   off += (size_t)(NN + 1) * 4;
    off = (off + 255) & ~(size_t)255;
    int*   csr_src = (int*)(ws + off);   off += (size_t)EE * 4;
    off = (off + 255) & ~(size_t)255;
    unsigned* base_u   = (unsigned*)(ws + off); off += (size_t)NC * 2;    // bf16 packed
    unsigned* bufA     = (unsigned*)(ws + off); off += (size_t)NC * 2;
    unsigned* bufB     = (unsigned*)(ws + off); off += (size_t)NC * 2;
    float*    smoothed = (float*)(ws + off);    off += (size_t)NC * 4;
    // tmp pair buffer (EE uint2 = 25.6 MB) aliases base_u+bufA (12.8+12.8 MB,
    // contiguous): dead before err_kernel writes them
    uint2* tmp = (uint2*)base_u;

    hipMemsetAsync(ws, 0, ZERO_BYTES, stream);

    detect_kernel<<<1, 256, 0, stream>>>(ytrue, mask, flags);
    prep_kernel<<<(NN * 64 + 255) / 256, 256, 0, stream>>>(ytrue, mask, flags, label, mask01);
    // ---- CSR build (bucket sort by dst) ----
    histA_kernel<<<NTILE, 256, 0, stream>>>(dst, bucket_tot);
    bscan_kernel<<<1, 512, 0, stream>>>(bucket_tot, bucket_base, bucket_fill);
    binA_kernel<<<NTILE, 512, 0, stream>>>(src, dst, bucket_fill, tmp);
    csrB_kernel<<<NB, 256, 0, stream>>>(tmp, bucket_base, row_ptr, norm, csr_src);
    // ---- initial error ----
    err_kernel<<<ERR_BLOCKS, 256, 0, stream>>>(ysoft, flags, label, mask01, norm, base_u, bufA, err_part);
    reduce_kernel<<<1, 1024, 0, stream>>>(mask01, err_part, scal);

    const int gather_blocks = (NN * 64 + 255) / 256;

    // ---- correct phase: 10 layers, alpha=0.979, clip [-1,1]
    unsigned* cur = bufA; unsigned* nxt = bufB;
    for (int l = 0; l < 10; l++) {
        int mode = (l < 9) ? 0 : 1;
        void* o = (l < 9) ? (void*)nxt : (void*)smoothed;
        gather_kernel<<<gather_blocks, 256, 0, stream>>>(row_ptr, csr_src, cur, base_u, norm, o,
                                                         rowsum, flags, 0.979f, -1.f, 1.f, mode);
        unsigned* t = cur; cur = nxt; nxt = t;
    }

    y0_kernel<<<ERR_BLOCKS, 256, 0, stream>>>(ysoft, flags, label, mask01, rowsum, scal, norm,
                                              smoothed, base_u, bufA);

    // ---- smooth phase: 10 layers, alpha=0.756, clip [0,1]; last writes d_out
    cur = bufA; nxt = bufB;
    for (int l = 0; l < 10; l++) {
        int mode = (l < 9) ? 0 : 3;
        void* o = (l < 9) ? (void*)nxt : (void*)d_out;
        gather_kernel<<<gather_blocks, 256, 0, stream>>>(row_ptr, csr_src, cur, base_u, norm, o,
                                                         rowsum, flags, 0.756f, 0.f, 1.f, mode);
        unsigned* t = cur; cur = nxt; nxt = t;
    }
}